// Round 8
// baseline (532.220 us; speedup 1.0000x reference)
//
#include <hip/hip_runtime.h>

// 2-layer tanh RNN, T=2048, B=4096, I=3, H=5. f32 storage.
//
// R13: R12 confirmed W ~ per-wave VALU cycles (solo SIMD is 4x19.7%=79%
// busy). v_pk_fma_f32 is HALF-RATE (full rate would exceed the 157TF fp32
// peak), so pk packing buys no FLOP throughput, and the quad layout burns
// 80 cy/step of fma for 5 units' worth (8 slots, 60% efficient).
// This version: 8 lanes/chain, SCALAR per-unit; lane l owns unit min(l,4)
// (lanes 5-7 duplicate unit 4 -- idle slots cost nothing in SIMT).
//   - per-lane fma: 18 x 2cy = 36 cy (vs 80)
//   - tanh x2 ~ 40 cy; total VALU ~ 84 cy/step (vs ~226)
//   - broadcast: 5 ds_swizzle/layer (DS pipe, PARALLEL to VALU; latency
//     hidden by R11's L0(t) || L1(t-1) interleave -- what R6 lacked)
// Per-unit accumulation order + tanh ops are a scalar replay of R12's pk
// components -> bit-identical, absmax must stay 0.00390625.

typedef float v3fu __attribute__((ext_vector_type(3), aligned(4)));

#define SEQ_T 2048
#define BATCH 4096
#define ISZ 3
#define HSZ 5
#define XSTRIDE (BATCH * ISZ)
#define OSTRIDE (BATCH * HSZ)

// broadcast lane (group8_base + K) to all 8 lanes of the group.
// BitMode: new_lane = (lane & 0x18) | K  (bit5 preserved automatically)
template<int K>
__device__ __forceinline__ float sw8(float v) {
    return __int_as_float(__builtin_amdgcn_ds_swizzle(
        __float_as_int(v), (K << 5) | 0x18));
}

__global__ __launch_bounds__(64, 1)
void rnn2_sc8(const float* __restrict__ x, const float* __restrict__ hx,
              const float* __restrict__ w_ih0, const float* __restrict__ w_hh0,
              const float* __restrict__ b_ih0, const float* __restrict__ b_hh0,
              const float* __restrict__ w_ih1, const float* __restrict__ w_hh1,
              const float* __restrict__ b_ih1, const float* __restrict__ b_hh1,
              float* __restrict__ out)
{
    const int tid = threadIdx.x;
    const int c   = (blockIdx.x * 64 + tid) >> 3;   // chain id, 0..4095
    const int l   = tid & 7;
    const int j   = (l < HSZ) ? l : (HSZ - 1);      // owned unit (5-7 dup 4)
    const float S = 2.8853900817779268f;            // 2*log2(e)

    // ---- per-lane scalar weight row (unit j), pre-scaled by S ----
    const float bias0 = S * (b_ih0[j] + b_hh0[j]);
    const float bias1 = S * (b_ih1[j] + b_hh1[j]);
    const float wi00 = S * w_ih0[j*ISZ+0], wi01 = S * w_ih0[j*ISZ+1], wi02 = S * w_ih0[j*ISZ+2];
    const float wh00 = S * w_hh0[j*HSZ+0], wh01 = S * w_hh0[j*HSZ+1], wh02 = S * w_hh0[j*HSZ+2],
                wh03 = S * w_hh0[j*HSZ+3], wh04 = S * w_hh0[j*HSZ+4];
    const float wi10 = S * w_ih1[j*HSZ+0], wi11 = S * w_ih1[j*HSZ+1], wi12 = S * w_ih1[j*HSZ+2],
                wi13 = S * w_ih1[j*HSZ+3], wi14 = S * w_ih1[j*HSZ+4];
    const float wh10 = S * w_hh1[j*HSZ+0], wh11 = S * w_hh1[j*HSZ+1], wh12 = S * w_hh1[j*HSZ+2],
                wh13 = S * w_hh1[j*HSZ+3], wh14 = S * w_hh1[j*HSZ+4];

    // ---- state: full broadcast vectors on every lane ----
    float h0b0 = hx[(size_t)c * HSZ + 0], h0b1 = hx[(size_t)c * HSZ + 1],
          h0b2 = hx[(size_t)c * HSZ + 2], h0b3 = hx[(size_t)c * HSZ + 3],
          h0b4 = hx[(size_t)c * HSZ + 4];
    const size_t hb1 = (size_t)BATCH * HSZ + (size_t)c * HSZ;
    float h1b0 = hx[hb1 + 0], h1b1 = hx[hb1 + 1], h1b2 = hx[hb1 + 2],
          h1b3 = hx[hb1 + 3], h1b4 = hx[hb1 + 4];

    // ---- x pipeline: depth 8, named v3 regs (dwordx3 loads) ----
    unsigned xoff = (unsigned)c * ISZ;
    v3fu x0 = *(const v3fu*)(x + xoff + 0*XSTRIDE);
    v3fu x1 = *(const v3fu*)(x + xoff + 1*XSTRIDE);
    v3fu x2 = *(const v3fu*)(x + xoff + 2*XSTRIDE);
    v3fu x3 = *(const v3fu*)(x + xoff + 3*XSTRIDE);
    v3fu x4 = *(const v3fu*)(x + xoff + 4*XSTRIDE);
    v3fu x5 = *(const v3fu*)(x + xoff + 5*XSTRIDE);
    v3fu x6 = *(const v3fu*)(x + xoff + 6*XSTRIDE);
    v3fu x7 = *(const v3fu*)(x + xoff + 7*XSTRIDE);
    xoff += 8 * XSTRIDE;

    unsigned ooff = (unsigned)c * HSZ + (unsigned)j;  // lane's out column

// PAIR: L0-dot(t) interleaved with L1-dot(t-1); both read h0b = h0(t-1).
// Scalar replay of R12's per-unit op order -> bit-identical results.
#define PAIR(XV, DOLOAD)                                                   \
    {                                                                      \
        const float xv0 = XV.x, xv1 = XV.y, xv2 = XV.z;                    \
        if (DOLOAD) {                                                      \
            XV = *(const v3fu*)(x + xoff);                                 \
            xoff += XSTRIDE;                                               \
        }                                                                  \
        float a = bias0, cc = 0.0f;                                        \
        float d = bias1, ee = 0.0f;                                        \
        a  = fmaf(xv0,  wi00, a);                                          \
        d  = fmaf(h0b0, wi10, d);                                          \
        cc = fmaf(xv1,  wi01, cc);                                         \
        ee = fmaf(h0b1, wi11, ee);                                         \
        a  = fmaf(xv2,  wi02, a);                                          \
        d  = fmaf(h0b2, wi12, d);                                          \
        cc = fmaf(h0b0, wh00, cc);                                         \
        ee = fmaf(h0b3, wi13, ee);                                         \
        a  = fmaf(h0b1, wh01, a);                                          \
        d  = fmaf(h0b4, wi14, d);                                          \
        cc = fmaf(h0b2, wh02, cc);                                         \
        ee = fmaf(h1b0, wh10, ee);                                         \
        a  = fmaf(h0b3, wh03, a);                                          \
        d  = fmaf(h1b1, wh11, d);                                          \
        cc = fmaf(h0b4, wh04, cc);                                         \
        ee = fmaf(h1b2, wh12, ee);                                         \
        a = a + cc;                                                        \
        d  = fmaf(h1b3, wh13, d);                                          \
        ee = fmaf(h1b4, wh14, ee);                                         \
        const float e0 = __builtin_amdgcn_exp2f(a);                        \
        d = d + ee;                                                        \
        const float e1 = __builtin_amdgcn_exp2f(d);                        \
        const float r0 = __builtin_amdgcn_rcpf(1.0f + e0);                 \
        const float r1 = __builtin_amdgcn_rcpf(1.0f + e1);                 \
        const float n0 = fmaf(-2.0f, r0, 1.0f);                           \
        const float n1 = fmaf(-2.0f, r1, 1.0f);                           \
        h0b0 = sw8<0>(n0);                                                 \
        h0b1 = sw8<1>(n0);                                                 \
        h0b2 = sw8<2>(n0);                                                 \
        h0b3 = sw8<3>(n0);                                                 \
        h0b4 = sw8<4>(n0);                                                 \
        out[ooff] = n1;                                                    \
        ooff += OSTRIDE;                                                   \
        h1b0 = sw8<0>(n1);                                                 \
        h1b1 = sw8<1>(n1);                                                 \
        h1b2 = sw8<2>(n1);                                                 \
        h1b3 = sw8<3>(n1);                                                 \
        h1b4 = sw8<4>(n1);                                                 \
    }

// L0-only (pipeline prologue, step 0)
#define P0ONLY(XV)                                                         \
    {                                                                      \
        const float xv0 = XV.x, xv1 = XV.y, xv2 = XV.z;                    \
        XV = *(const v3fu*)(x + xoff);                                     \
        xoff += XSTRIDE;                                                   \
        float a = bias0, cc = 0.0f;                                        \
        a  = fmaf(xv0,  wi00, a);                                          \
        cc = fmaf(xv1,  wi01, cc);                                         \
        a  = fmaf(xv2,  wi02, a);                                          \
        cc = fmaf(h0b0, wh00, cc);                                         \
        a  = fmaf(h0b1, wh01, a);                                          \
        cc = fmaf(h0b2, wh02, cc);                                         \
        a  = fmaf(h0b3, wh03, a);                                          \
        cc = fmaf(h0b4, wh04, cc);                                         \
        a = a + cc;                                                        \
        const float e0 = __builtin_amdgcn_exp2f(a);                        \
        const float r0 = __builtin_amdgcn_rcpf(1.0f + e0);                 \
        const float n0 = fmaf(-2.0f, r0, 1.0f);                           \
        h0b0 = sw8<0>(n0);                                                 \
        h0b1 = sw8<1>(n0);                                                 \
        h0b2 = sw8<2>(n0);                                                 \
        h0b3 = sw8<3>(n0);                                                 \
        h0b4 = sw8<4>(n0);                                                 \
    }

    // ---- prologue: P0(0); then pairs P0(1..7)|P1(0..6), refilling ----
    P0ONLY(x0)
    PAIR(x1, 1)
    PAIR(x2, 1)
    PAIR(x3, 1)
    PAIR(x4, 1)
    PAIR(x5, 1)
    PAIR(x6, 1)
    PAIR(x7, 1)

    // ---- steady: blocks 1..254, refilling 8 steps ahead ----
    for (int blk = 1; blk < SEQ_T / 8 - 1; ++blk) {
        PAIR(x0, 1)
        PAIR(x1, 1)
        PAIR(x2, 1)
        PAIR(x3, 1)
        PAIR(x4, 1)
        PAIR(x5, 1)
        PAIR(x6, 1)
        PAIR(x7, 1)
    }

    // ---- final block 255: steps 2040..2047, no refill ----
    PAIR(x0, 0)
    PAIR(x1, 0)
    PAIR(x2, 0)
    PAIR(x3, 0)
    PAIR(x4, 0)
    PAIR(x5, 0)
    PAIR(x6, 0)
    PAIR(x7, 0)

    // ---- epilogue: P1(2047) (uses h0b = h0(2047), h1b = h1(2046)) ----
    {
        float d = bias1, ee = 0.0f;
        d  = fmaf(h0b0, wi10, d);
        ee = fmaf(h0b1, wi11, ee);
        d  = fmaf(h0b2, wi12, d);
        ee = fmaf(h0b3, wi13, ee);
        d  = fmaf(h0b4, wi14, d);
        ee = fmaf(h1b0, wh10, ee);
        d  = fmaf(h1b1, wh11, d);
        ee = fmaf(h1b2, wh12, ee);
        d  = fmaf(h1b3, wh13, d);
        ee = fmaf(h1b4, wh14, ee);
        d = d + ee;
        const float e1 = __builtin_amdgcn_exp2f(d);
        const float r1 = __builtin_amdgcn_rcpf(1.0f + e1);
        const float n1 = fmaf(-2.0f, r1, 1.0f);
        out[ooff] = n1;
        h1b0 = sw8<0>(n1);
        h1b1 = sw8<1>(n1);
        h1b2 = sw8<2>(n1);
        h1b3 = sw8<3>(n1);
        h1b4 = sw8<4>(n1);
    }
#undef PAIR
#undef P0ONLY

    // h_n = [h0_final, h1_final] after out[T,B,H]; 8x dup stores benign
    float* hn = out + (size_t)SEQ_T * BATCH * HSZ;
    hn[(size_t)c * HSZ + 0] = h0b0;
    hn[(size_t)c * HSZ + 1] = h0b1;
    hn[(size_t)c * HSZ + 2] = h0b2;
    hn[(size_t)c * HSZ + 3] = h0b3;
    hn[(size_t)c * HSZ + 4] = h0b4;
    hn[hb1 + 0] = h1b0;
    hn[hb1 + 1] = h1b1;
    hn[hb1 + 2] = h1b2;
    hn[hb1 + 3] = h1b3;
    hn[hb1 + 4] = h1b4;
}

extern "C" void kernel_launch(void* const* d_in, const int* in_sizes, int n_in,
                              void* d_out, int out_size, void* d_ws, size_t ws_size,
                              hipStream_t stream) {
    // 4096 chains x 8 lanes = 32768 threads; 64-thread blocks -> 512 blocks,
    // 2 waves/CU on separate SIMDs.
    rnn2_sc8<<<(BATCH * 8) / 64, 64, 0, stream>>>(
        (const float*)d_in[0], (const float*)d_in[1],
        (const float*)d_in[2], (const float*)d_in[3],
        (const float*)d_in[4], (const float*)d_in[5],
        (const float*)d_in[6], (const float*)d_in[7],
        (const float*)d_in[8], (const float*)d_in[9],
        (float*)d_out);
}

// Round 9
// 403.713 us; speedup vs baseline: 1.3183x; 1.3183x over previous
//
#include <hip/hip_runtime.h>

// 2-layer tanh RNN, T=2048, B=4096, I=3, H=5. f32 storage.
//
// R14: producer/consumer retry (R10) with the two diagnosed bugs fixed.
// R13 proved ds_swizzle broadcast is poison (DS pipe); R12's quad+DPP+pk
// body is ~79% VALU-issue-busy -> only a second SIMD per chain cuts W.
// R10's failure causes, both fixed here:
//  (1) __syncthreads drains vmcnt(0); R10 issued x loads ROLLING inside
//      the 8 steps, so each barrier ate a fresh ~900cy HBM latency.
//      Fix: batch 8x global_load_dwordx3 at block top (double-buffered
//      named register sets XA/XB) -> loads are ~900cy old at the drain.
//  (2) ring row stride 40B -> b64 writes hit even banks only (4-way
//      conflict, 2.1M measured). Fix: stride 48B -> 8B-aligned b64,
//      <=2-way aliasing (free, m136).
// Wave0 = layer0 (R12 body minus L1), writes h0 pairs to LDS ring.
// Wave1 = layer1 + out stores, one 8-step block behind, 1-step LDS
// prefetch. Math is bit-identical to R12 (same pk slots (ja,ja+1), same
// per-unit op order, h0 passes as exact f32) -> absmax 0.00390625.

typedef float v2f  __attribute__((ext_vector_type(2)));
typedef float v2fu __attribute__((ext_vector_type(2), aligned(4)));
typedef float v3fu __attribute__((ext_vector_type(3), aligned(4)));

#define SEQ_T 2048
#define BATCH 4096
#define ISZ 3
#define HSZ 5
#define TBLK 8
#define NSUP (SEQ_T / TBLK)       // 256
#define XSTRIDE (BATCH * ISZ)
#define OSTRIDE (BATCH * HSZ)

template<int K>
__device__ __forceinline__ float qbcast(float v) {
    return __int_as_float(__builtin_amdgcn_mov_dpp(
        __float_as_int(v), K * 0x55, 0xF, 0xF, false));
}
__device__ __forceinline__ v2f vsplat(float s) { return (v2f){s, s}; }
__device__ __forceinline__ v2f vfma(float s, v2f w, v2f a) {
    return __builtin_elementwise_fma(vsplat(s), w, a);  // v_pk_fma_f32
}

__global__ __launch_bounds__(128, 1)
void rnn2_pc(const float* __restrict__ x, const float* __restrict__ hx,
             const float* __restrict__ w_ih0, const float* __restrict__ w_hh0,
             const float* __restrict__ b_ih0, const float* __restrict__ b_hh0,
             const float* __restrict__ w_ih1, const float* __restrict__ w_hh1,
             const float* __restrict__ b_ih1, const float* __restrict__ b_hh1,
             float* __restrict__ out)
{
    // ring[buf][step][chain_local][12]: row stride 48B (8B-aligned b64
    // writes at [cl][ja*2], start banks 12cl+2ja mod 32 -> <=2-way).
    __shared__ float ring[2][TBLK][16][12];

    const int tid  = threadIdx.x;
    const int wid  = tid >> 6;                      // 0 = L0 prod, 1 = L1 cons
    const int lane = tid & 63;
    const int cl   = lane >> 2;                     // chain-local 0..15
    const int ja   = lane & 3;                      // slot A unit
    const int jb   = ja + 1;                        // slot B unit
    const int c    = blockIdx.x * 16 + cl;          // chain id
    const float S  = 2.8853900817779268f;           // 2*log2(e)

    // ---- weight pairs (ja,jb rows), pre-scaled; both waves load all ----
    const v2f bias0p = (v2f){ S * (b_ih0[ja] + b_hh0[ja]), S * (b_ih0[jb] + b_hh0[jb]) };
    const v2f bias1p = (v2f){ S * (b_ih1[ja] + b_hh1[ja]), S * (b_ih1[jb] + b_hh1[jb]) };
#define LW(W, k, n)  (v2f){ S * W[ja * (n) + (k)], S * W[jb * (n) + (k)] }
    const v2f wi0p0 = LW(w_ih0, 0, ISZ), wi0p1 = LW(w_ih0, 1, ISZ), wi0p2 = LW(w_ih0, 2, ISZ);
    const v2f wh0p0 = LW(w_hh0, 0, HSZ), wh0p1 = LW(w_hh0, 1, HSZ), wh0p2 = LW(w_hh0, 2, HSZ),
              wh0p3 = LW(w_hh0, 3, HSZ), wh0p4 = LW(w_hh0, 4, HSZ);
    const v2f wi1p0 = LW(w_ih1, 0, HSZ), wi1p1 = LW(w_ih1, 1, HSZ), wi1p2 = LW(w_ih1, 2, HSZ),
              wi1p3 = LW(w_ih1, 3, HSZ), wi1p4 = LW(w_ih1, 4, HSZ);
    const v2f wh1p0 = LW(w_hh1, 0, HSZ), wh1p1 = LW(w_hh1, 1, HSZ), wh1p2 = LW(w_hh1, 2, HSZ),
              wh1p3 = LW(w_hh1, 3, HSZ), wh1p4 = LW(w_hh1, 4, HSZ);
#undef LW

    // ---- state ----
    float h0b0 = hx[(size_t)c * HSZ + 0], h0b1 = hx[(size_t)c * HSZ + 1],
          h0b2 = hx[(size_t)c * HSZ + 2], h0b3 = hx[(size_t)c * HSZ + 3],
          h0b4 = hx[(size_t)c * HSZ + 4];
    const size_t hb1 = (size_t)BATCH * HSZ + (size_t)c * HSZ;
    float h1b0 = hx[hb1 + 0], h1b1 = hx[hb1 + 1], h1b2 = hx[hb1 + 2],
          h1b3 = hx[hb1 + 3], h1b4 = hx[hb1 + 4];

    // ---- x block buffers: two named sets of 8 v3 regs (producer) ----
    unsigned xoff = (unsigned)c * ISZ;
    v3fu xA0, xA1, xA2, xA3, xA4, xA5, xA6, xA7;
    v3fu xB0, xB1, xB2, xB3, xB4, xB5, xB6, xB7;
#define LOADX(P)                                                           \
    {                                                                      \
        P##0 = *(const v3fu*)(x + xoff + 0*XSTRIDE);                       \
        P##1 = *(const v3fu*)(x + xoff + 1*XSTRIDE);                       \
        P##2 = *(const v3fu*)(x + xoff + 2*XSTRIDE);                       \
        P##3 = *(const v3fu*)(x + xoff + 3*XSTRIDE);                       \
        P##4 = *(const v3fu*)(x + xoff + 4*XSTRIDE);                       \
        P##5 = *(const v3fu*)(x + xoff + 5*XSTRIDE);                       \
        P##6 = *(const v3fu*)(x + xoff + 6*XSTRIDE);                       \
        P##7 = *(const v3fu*)(x + xoff + 7*XSTRIDE);                       \
        xoff += 8u * XSTRIDE;                                              \
    }

    unsigned ooff = (unsigned)c * HSZ + (unsigned)ja;   // consumer out ptr
    float g0, g1, g2, g3, g4;                           // consumer h0 stage

// producer step: L0 for slots (ja, jb); R12's exact op order; ring write
#define STEP0(XV, WR, TT)                                                  \
    {                                                                      \
        v2f a = bias0p, cc = (v2f){0.0f, 0.0f};                            \
        a  = vfma(XV.x,  wi0p0, a);                                        \
        cc = vfma(XV.y,  wi0p1, cc);                                       \
        a  = vfma(XV.z,  wi0p2, a);                                        \
        cc = vfma(h0b0, wh0p0, cc);                                        \
        a  = vfma(h0b1, wh0p1, a);                                         \
        cc = vfma(h0b2, wh0p2, cc);                                        \
        a  = vfma(h0b3, wh0p3, a);                                         \
        cc = vfma(h0b4, wh0p4, cc);                                        \
        a = a + cc;                                                        \
        v2f e0;                                                            \
        e0.x = __builtin_amdgcn_exp2f(a.x);                                \
        e0.y = __builtin_amdgcn_exp2f(a.y);                                \
        const v2f p0 = e0 + vsplat(1.0f);                                  \
        v2f r0;                                                            \
        r0.x = __builtin_amdgcn_rcpf(p0.x);                                \
        r0.y = __builtin_amdgcn_rcpf(p0.y);                                \
        const v2f n0 = __builtin_elementwise_fma(vsplat(-2.0f), r0, vsplat(1.0f)); \
        h0b0 = qbcast<0>(n0.x);                                            \
        h0b1 = qbcast<1>(n0.x);                                            \
        h0b2 = qbcast<2>(n0.x);                                            \
        h0b3 = qbcast<3>(n0.x);                                            \
        h0b4 = qbcast<3>(n0.y);                                            \
        *(v2f*)&WR[TT][cl][ja * 2] = n0;                                   \
    }

#define PBLOCK(P, RB)                                                      \
    {                                                                      \
        float (*wr)[16][12] = ring[RB];                                    \
        STEP0(P##0, wr, 0)                                                 \
        STEP0(P##1, wr, 1)                                                 \
        STEP0(P##2, wr, 2)                                                 \
        STEP0(P##3, wr, 3)                                                 \
        STEP0(P##4, wr, 4)                                                 \
        STEP0(P##5, wr, 5)                                                 \
        STEP0(P##6, wr, 6)                                                 \
        STEP0(P##7, wr, 7)                                                 \
    }

// consumer step: L1 from staged h0 (g*), R12's exact op order; store
#define STEP1(RD, TT, DOPRE)                                               \
    {                                                                      \
        const float u0 = g0, u1 = g1, u2 = g2, u3 = g3, u4 = g4;           \
        if (DOPRE) {                                                       \
            g0 = RD[(TT) + 1][cl][0];                                      \
            g1 = RD[(TT) + 1][cl][2];                                      \
            g2 = RD[(TT) + 1][cl][4];                                      \
            g3 = RD[(TT) + 1][cl][6];                                      \
            g4 = RD[(TT) + 1][cl][7];                                      \
        }                                                                  \
        v2f d = bias1p, ee = (v2f){0.0f, 0.0f};                            \
        d  = vfma(u0,   wi1p0, d);                                         \
        ee = vfma(u1,   wi1p1, ee);                                        \
        d  = vfma(u2,   wi1p2, d);                                         \
        ee = vfma(u3,   wi1p3, ee);                                        \
        d  = vfma(u4,   wi1p4, d);                                         \
        ee = vfma(h1b0, wh1p0, ee);                                        \
        d  = vfma(h1b1, wh1p1, d);                                         \
        ee = vfma(h1b2, wh1p2, ee);                                        \
        d  = vfma(h1b3, wh1p3, d);                                         \
        ee = vfma(h1b4, wh1p4, ee);                                        \
        d = d + ee;                                                        \
        v2f e1;                                                            \
        e1.x = __builtin_amdgcn_exp2f(d.x);                                \
        e1.y = __builtin_amdgcn_exp2f(d.y);                                \
        const v2f p1 = e1 + vsplat(1.0f);                                  \
        v2f r1;                                                            \
        r1.x = __builtin_amdgcn_rcpf(p1.x);                                \
        r1.y = __builtin_amdgcn_rcpf(p1.y);                                \
        const v2f n1 = __builtin_elementwise_fma(vsplat(-2.0f), r1, vsplat(1.0f)); \
        *(v2fu*)(out + ooff) = n1;                                         \
        ooff += OSTRIDE;                                                   \
        h1b0 = qbcast<0>(n1.x);                                            \
        h1b1 = qbcast<1>(n1.x);                                            \
        h1b2 = qbcast<2>(n1.x);                                            \
        h1b3 = qbcast<3>(n1.x);                                            \
        h1b4 = qbcast<3>(n1.y);                                            \
    }

#define CBLOCK(RB)                                                         \
    {                                                                      \
        const float (*rd)[16][12] = ring[RB];                              \
        g0 = rd[0][cl][0];                                                 \
        g1 = rd[0][cl][2];                                                 \
        g2 = rd[0][cl][4];                                                 \
        g3 = rd[0][cl][6];                                                 \
        g4 = rd[0][cl][7];                                                 \
        STEP1(rd, 0, 1)                                                    \
        STEP1(rd, 1, 1)                                                    \
        STEP1(rd, 2, 1)                                                    \
        STEP1(rd, 3, 1)                                                    \
        STEP1(rd, 4, 1)                                                    \
        STEP1(rd, 5, 1)                                                    \
        STEP1(rd, 6, 1)                                                    \
        STEP1(rd, 7, 0)                                                    \
    }

    // ---- prologue: block 0 into XA (waits naturally at first use) ----
    LOADX(xA)

    // si = 0: producer computes block 0 (ring[0]); issues block-1 loads
    __syncthreads();
    if (wid == 0) { LOADX(xB) PBLOCK(xA, 0) }

    // steady pairs: si = 1..254 (127 pairs)
    for (int sp = 0; sp < 127; ++sp) {
        __syncthreads();                       // odd si: buf1 write, buf0 read
        if (wid == 0) { LOADX(xA) PBLOCK(xB, 1) } else { CBLOCK(0) }
        __syncthreads();                       // even si: buf0 write, buf1 read
        if (wid == 0) { LOADX(xB) PBLOCK(xA, 0) } else { CBLOCK(1) }
    }

    // si = 255: producer's last block (no further loads)
    __syncthreads();
    if (wid == 0) { PBLOCK(xB, 1) } else { CBLOCK(0) }

    // si = 256: consumer drains the final block
    __syncthreads();
    if (wid != 0) { CBLOCK(1) }

#undef STEP0
#undef STEP1
#undef PBLOCK
#undef CBLOCK
#undef LOADX

    // h_n = [h0_final, h1_final] after out[T,B,H]; quad-dup stores benign
    float* hn = out + (size_t)SEQ_T * BATCH * HSZ;
    if (wid == 0) {
        hn[(size_t)c * HSZ + 0] = h0b0;
        hn[(size_t)c * HSZ + 1] = h0b1;
        hn[(size_t)c * HSZ + 2] = h0b2;
        hn[(size_t)c * HSZ + 3] = h0b3;
        hn[(size_t)c * HSZ + 4] = h0b4;
    } else {
        hn[hb1 + 0] = h1b0;
        hn[hb1 + 1] = h1b1;
        hn[hb1 + 2] = h1b2;
        hn[hb1 + 3] = h1b3;
        hn[hb1 + 4] = h1b4;
    }
}

extern "C" void kernel_launch(void* const* d_in, const int* in_sizes, int n_in,
                              void* d_out, int out_size, void* d_ws, size_t ws_size,
                              hipStream_t stream) {
    // 256 blocks x 128 threads: 16 chains/block; wave0 = L0, wave1 = L1.
    rnn2_pc<<<BATCH / 16, 128, 0, stream>>>(
        (const float*)d_in[0], (const float*)d_in[1],
        (const float*)d_in[2], (const float*)d_in[3],
        (const float*)d_in[4], (const float*)d_in[5],
        (const float*)d_in[6], (const float*)d_in[7],
        (const float*)d_in[8], (const float*)d_in[9],
        (float*)d_out);
}